// Round 13
// baseline (730.064 us; speedup 1.0000x reference)
//
#include <hip/hip_runtime.h>
#include <math.h>
#include <stdint.h>

// B=8,S=2048,D=512,I=1024,E=8,K=2,SH=2048 ; T=16384 tokens
#define T_TOK 16384
#define DDIM  512
#define IDIM  1024
#define NEXP  8
#define SHDIM 2048
#define MT_R  264                  // routed M-tiles (2T + 8*127 padded to 128)
#define MPAD  (MT_R * 128)         // 33792 padded routed rows
#define GBLK  256                  // k_gate blocks (64 tokens each)

typedef unsigned short u16;
typedef short bf16x8 __attribute__((ext_vector_type(8)));
typedef float f32x4 __attribute__((ext_vector_type(4)));

#define MFMA16(a, b, c) __builtin_amdgcn_mfma_f32_16x16x32_bf16((a), (b), (c), 0, 0, 0)

__device__ __forceinline__ u16 f2bf(float f) {
    unsigned u = __float_as_uint(f);
    u += 0x7FFF + ((u >> 16) & 1);   // round-to-nearest-even
    return (u16)(u >> 16);
}
__device__ __forceinline__ float bf2f(u16 h) {
    return __uint_as_float((unsigned)h << 16);
}

// XCD-chunked bijective block swizzle (T1); nwg % 8 == 0 for all our grids.
__device__ __forceinline__ int xcd_swz(int id, int nwg) {
    return (id & 7) * (nwg >> 3) + (id >> 3);
}

// ---------------- routing ----------------
// 64 tokens/block, 4 waves. No global atomics; fuses x->bf16 (writes xb).
__global__ __launch_bounds__(256) void k_gate(
    const float* __restrict__ x, const float* __restrict__ gw,
    int* __restrict__ topi, float* __restrict__ wts,
    int* __restrict__ pcnt, float* __restrict__ pps, u16* __restrict__ xb)
{
    __shared__ int   cnt[NEXP];
    __shared__ float ps[NEXP];
    const int tid = threadIdx.x;
    if (tid < NEXP) { cnt[tid] = 0; ps[tid] = 0.f; }
    __syncthreads();
    const int wid = tid >> 6, lane = tid & 63;

    const float4* gw4 = (const float4*)gw;
    float4 g0[NEXP], g1[NEXP];
#pragma unroll
    for (int e = 0; e < NEXP; e++) {
        g0[e] = gw4[e * 128 + lane];
        g1[e] = gw4[e * 128 + 64 + lane];
    }

    const int t0 = blockIdx.x * 64 + wid * 16;
    for (int u = 0; u < 16; u++) {
        int t = t0 + u;
        const float4* xr4 = (const float4*)(x + (size_t)t * DDIM);
        float4 v0 = xr4[lane];
        float4 v1 = xr4[64 + lane];
        ushort4 o0 = { f2bf(v0.x), f2bf(v0.y), f2bf(v0.z), f2bf(v0.w) };
        ushort4 o1 = { f2bf(v1.x), f2bf(v1.y), f2bf(v1.z), f2bf(v1.w) };
        ushort4* xbo = (ushort4*)(xb + (size_t)t * DDIM);
        xbo[lane] = o0;
        xbo[64 + lane] = o1;
        float acc[NEXP];
#pragma unroll
        for (int e = 0; e < NEXP; e++) {
            acc[e] = v0.x * g0[e].x + v0.y * g0[e].y + v0.z * g0[e].z + v0.w * g0[e].w
                   + v1.x * g1[e].x + v1.y * g1[e].y + v1.z * g1[e].z + v1.w * g1[e].w;
        }
#pragma unroll
        for (int e = 0; e < NEXP; e++) {
#pragma unroll
            for (int off = 32; off; off >>= 1) acc[e] += __shfl_xor(acc[e], off, 64);
        }
        if (lane == 0) {
            float s[NEXP];
#pragma unroll
            for (int e = 0; e < NEXP; e++) s[e] = 1.f / (1.f + expf(-acc[e]));
            int i1 = 0; float v1s = s[0];
#pragma unroll
            for (int e = 1; e < NEXP; e++) if (s[e] > v1s) { v1s = s[e]; i1 = e; }
            int i2 = -1; float v2s = -1.f;
#pragma unroll
            for (int e = 0; e < NEXP; e++) if (e != i1 && s[e] > v2s) { v2s = s[e]; i2 = e; }
            float inv = 1.f / (v1s + v2s);
            float wa = v1s * inv, wb = v2s * inv;  // ROUTE_SCALE = 1.0
            topi[2 * t] = i1; topi[2 * t + 1] = i2;
            wts[2 * t] = wa;  wts[2 * t + 1] = wb;
            atomicAdd(&cnt[i1], 1); atomicAdd(&cnt[i2], 1);   // LDS atomics
            atomicAdd(&ps[i1], wa); atomicAdd(&ps[i2], wb);
        }
    }
    __syncthreads();
    if (tid < NEXP) {
        pcnt[blockIdx.x * NEXP + tid] = cnt[tid];
        pps[blockIdx.x * NEXP + tid]  = ps[tid];
    }
}

// Reduce per-block partials; 128-padded exclusive prefix; aux loss; zero cursors.
__global__ void k_scan(const int* __restrict__ pcnt, const float* __restrict__ pps,
                       int* __restrict__ off_pad, float* __restrict__ out_loss,
                       int* __restrict__ cursors)
{
    __shared__ int   scnt[8][NEXP];
    __shared__ float sps[8][NEXP];
    int tid = threadIdx.x;
    if (tid < NEXP) cursors[tid] = 0;
    if (tid < 64) {
        int e = tid & 7, part = tid >> 3;
        int c = 0; float p = 0.f;
        for (int b = part * 32; b < part * 32 + 32; b++) {
            c += pcnt[b * NEXP + e];
            p += pps[b * NEXP + e];
        }
        scnt[part][e] = c; sps[part][e] = p;
    }
    __syncthreads();
    if (tid == 0) {
        int off = 0; float L = 0.f;
        for (int e = 0; e < NEXP; e++) {
            int c = 0; float p = 0.f;
            for (int q = 0; q < 8; q++) { c += scnt[q][e]; p += sps[q][e]; }
            off_pad[e] = off;
            off += (c + 127) & ~127;
            float f = (float)NEXP * (float)c / (float)(2 * T_TOK);
            L += f * (p / (float)T_TOK);
        }
        off_pad[NEXP] = off;
        out_loss[0] = L;
    }
}

// fills perm with -1; also zeroes the 512-elem bf16 zero-page
__global__ void k_fillperm(int* __restrict__ perm, u16* __restrict__ zpad) {
    int i = blockIdx.x * blockDim.x + threadIdx.x;
    if (i < MPAD) perm[i] = -1;
    if (blockIdx.x == 0 && threadIdx.x < 256) ((unsigned*)zpad)[threadIdx.x] = 0u;
}

// 256 tokens/block: LDS histogram -> one global atomicAdd per expert per block.
__global__ __launch_bounds__(256) void k_scatter(
    const int* __restrict__ topi, const float* __restrict__ wts,
    const int* __restrict__ off_pad, int* __restrict__ cursors,
    int* __restrict__ perm, float* __restrict__ pw, int* __restrict__ inv)
{
    __shared__ int lcnt[NEXP];
    __shared__ int lbase[NEXP];
    int tid = threadIdx.x;
    if (tid < NEXP) lcnt[tid] = 0;
    __syncthreads();
    int t = blockIdx.x * 256 + tid;
    int e0 = topi[2 * t], e1 = topi[2 * t + 1];
    int p0 = atomicAdd(&lcnt[e0], 1);
    int p1 = atomicAdd(&lcnt[e1], 1);
    __syncthreads();
    if (tid < NEXP) lbase[tid] = atomicAdd(&cursors[tid], lcnt[tid]);
    __syncthreads();
    int s0 = off_pad[e0] + lbase[e0] + p0;
    int s1 = off_pad[e1] + lbase[e1] + p1;
    perm[s0] = t; pw[s0] = wts[2 * t];
    perm[s1] = t; pw[s1] = wts[2 * t + 1];
    inv[2 * t] = s0; inv[2 * t + 1] = s1;
}

// dst[z][c][r] = bf16(src[z][r][c]) ; grid (C/64, R/64, nmat)
__global__ __launch_bounds__(256) void k_transpose(const float* __restrict__ src,
                                                   u16* __restrict__ dst, int R, int C)
{
    __shared__ u16 t[64][68];
    const float* s = src + (size_t)blockIdx.z * R * C;
    u16* d = dst + (size_t)blockIdx.z * R * C;
    int r0 = blockIdx.y * 64, c0 = blockIdx.x * 64;
    int tid = threadIdx.x;
    int lr = tid >> 4, lc = (tid & 15) * 4;
#pragma unroll
    for (int u = 0; u < 4; u++) {
        int r = lr + u * 16;
        float4 v = *(const float4*)&s[(size_t)(r0 + r) * C + c0 + lc];
        t[lc + 0][r] = f2bf(v.x);
        t[lc + 1][r] = f2bf(v.y);
        t[lc + 2][r] = f2bf(v.z);
        t[lc + 3][r] = f2bf(v.w);
    }
    __syncthreads();
    int wr = tid >> 4, wc = (tid & 15) * 4;
#pragma unroll
    for (int u = 0; u < 4; u++) {
        int c = wr + u * 16;
        ushort4 o = { t[c][wc], t[c][wc + 1], t[c][wc + 2], t[c][wc + 3] };
        *(ushort4*)&d[(size_t)(c0 + c) * R + r0 + wc] = o;
    }
}

// ======== direct-to-register GEMMs: no LDS, no barriers; each wave free-runs ========
// Fragment layout == lane-contiguous 16B in [N][K]/[M][K]: load straight to VGPR.
// Ping-pong frag sets, distance-1 prefetch (WAR-safe under in-order issue).

// ---- s1: block 128(M)x128(Bcols) = 2x2 waves; wave 64x64 DUAL (C1+C3) ----
template<bool ROUTED, bool BIAS, int GXB>
__global__ __launch_bounds__(256, 2) void g_s1(
    const u16* __restrict__ Axb, const u16* __restrict__ B1t, const u16* __restrict__ B3t,
    const float* __restrict__ bias1, const float* __restrict__ bias3,
    u16* __restrict__ H, int ldh, const int* __restrict__ off_pad,
    const int* __restrict__ perm, const u16* __restrict__ zpad)
{
    const int nwg = GXB * gridDim.y;
    const int id  = xcd_swz(blockIdx.y * GXB + blockIdx.x, nwg);
    const int m0 = (id / GXB) * 128;
    const int n0 = (id % GXB) * 128;
    if (ROUTED && m0 >= off_pad[NEXP]) return;
    const u16* b1 = B1t; const u16* b3 = B3t;
    if (ROUTED) {
        int e = 0;
        while (off_pad[e + 1] <= m0) e++;
        b1 += (size_t)e * IDIM * DDIM;
        b3 += (size_t)e * IDIM * DDIM;
    }
    const int lane = threadIdx.x & 63, wid = threadIdx.x >> 6;
    const int wm = wid >> 1, wn = wid & 1;
    const int fr = lane & 15, hi = lane >> 4;

    const u16* pa[4]; const u16* pb1[4]; const u16* pb3[4];
#pragma unroll
    for (int i = 0; i < 4; i++) {
        int row = m0 + wm * 64 + i * 16 + fr;
        if (ROUTED) {
            int tok = perm[row];
            pa[i] = (tok >= 0 ? Axb + (size_t)tok * DDIM : zpad) + hi * 8;
        } else {
            pa[i] = Axb + (size_t)row * DDIM + hi * 8;
        }
        int br = n0 + wn * 64 + i * 16 + fr;
        pb1[i] = b1 + (size_t)br * DDIM + hi * 8;
        pb3[i] = b3 + (size_t)br * DDIM + hi * 8;
    }

    f32x4 acc1[4][4], acc3[4][4];
#pragma unroll
    for (int i = 0; i < 4; i++)
#pragma unroll
        for (int j = 0; j < 4; j++) { acc1[i][j] = {0.f, 0.f, 0.f, 0.f}; acc3[i][j] = {0.f, 0.f, 0.f, 0.f}; }

    bf16x8 fa[2][4], fb1[2][4], fb3[2][4];
#pragma unroll
    for (int i = 0; i < 4; i++) {
        fa[0][i]  = *(const bf16x8*)(pa[i]);
        fb1[0][i] = *(const bf16x8*)(pb1[i]);
        fb3[0][i] = *(const bf16x8*)(pb3[i]);
    }
    const int NT = DDIM / 32;   // 16, fully unrolled
#pragma unroll
    for (int t = 0; t < NT; t++) {
        const int cs = t & 1, ns = cs ^ 1;
        if (t + 1 < NT) {
            const int ko = (t + 1) * 32;
#pragma unroll
            for (int i = 0; i < 4; i++) {
                fa[ns][i]  = *(const bf16x8*)(pa[i]  + ko);
                fb1[ns][i] = *(const bf16x8*)(pb1[i] + ko);
                fb3[ns][i] = *(const bf16x8*)(pb3[i] + ko);
            }
        }
#pragma unroll
        for (int i = 0; i < 4; i++)
#pragma unroll
            for (int j = 0; j < 4; j++) {
                acc1[i][j] = MFMA16(fa[cs][i], fb1[cs][j], acc1[i][j]);
                acc3[i][j] = MFMA16(fa[cs][i], fb3[cs][j], acc3[i][j]);
            }
    }

    // wave-local SwiGLU epilogue
#pragma unroll
    for (int i = 0; i < 4; i++) {
#pragma unroll
        for (int j = 0; j < 4; j++) {
            int col = n0 + wn * 64 + j * 16 + fr;
            float bb1 = BIAS ? bias1[col] : 0.f;
            float bb3 = BIAS ? bias3[col] : 0.f;
#pragma unroll
            for (int r = 0; r < 4; r++) {
                int row = m0 + wm * 64 + i * 16 + hi * 4 + r;
                float v1 = acc1[i][j][r] + bb1;
                float v3 = acc3[i][j][r] + bb3;
                float hv = (v1 / (1.f + __expf(-v1))) * v3;
                H[(size_t)row * ldh + col] = f2bf(hv);
            }
        }
    }
}

// ---- s2: block 128(M)x256(N) = 2x2 waves; wave 64x128 ----
// EPI 1: out = C + bias2 (f32).  EPI 2: ytmp = bf16(C) (routed).
template<int K, int EPI, int GXB>
__global__ __launch_bounds__(256, 2) void g_s2(
    const u16* __restrict__ A, const u16* __restrict__ Bt,
    const float* __restrict__ bias2, float* __restrict__ out,
    u16* __restrict__ ytmp, const int* __restrict__ off_pad)
{
    constexpr bool ROUTED = (EPI == 2);
    const int nwg = GXB * gridDim.y;
    const int id  = xcd_swz(blockIdx.y * GXB + blockIdx.x, nwg);
    const int m0 = (id / GXB) * 128;
    const int n0 = (id % GXB) * 256;
    if (ROUTED && m0 >= off_pad[NEXP]) return;
    const u16* bt = Bt;
    if (ROUTED) {
        int e = 0;
        while (off_pad[e + 1] <= m0) e++;
        bt += (size_t)e * DDIM * IDIM;
    }
    const int lane = threadIdx.x & 63, wid = threadIdx.x >> 6;
    const int wm = wid >> 1, wn = wid & 1;
    const int fr = lane & 15, hi = lane >> 4;

    const u16* pa[4]; const u16* pb[8];
#pragma unroll
    for (int i = 0; i < 4; i++)
        pa[i] = A + (size_t)(m0 + wm * 64 + i * 16 + fr) * K + hi * 8;
#pragma unroll
    for (int j = 0; j < 8; j++)
        pb[j] = bt + (size_t)(n0 + wn * 128 + j * 16 + fr) * K + hi * 8;

    f32x4 acc[4][8];
#pragma unroll
    for (int i = 0; i < 4; i++)
#pragma unroll
        for (int j = 0; j < 8; j++) acc[i][j] = {0.f, 0.f, 0.f, 0.f};

    bf16x8 fa[2][4], fb[2][8];
#pragma unroll
    for (int i = 0; i < 4; i++) fa[0][i] = *(const bf16x8*)(pa[i]);
#pragma unroll
    for (int j = 0; j < 8; j++) fb[0][j] = *(const bf16x8*)(pb[j]);

    const int NT = K / 32;
    for (int kb = 0; kb < NT - 4; kb += 4) {
#pragma unroll
        for (int u = 0; u < 4; u++) {
            const int cs = u & 1, ns = cs ^ 1;
            const int ko = (u + 1) * 32;
#pragma unroll
            for (int i = 0; i < 4; i++) fa[ns][i] = *(const bf16x8*)(pa[i] + ko);
#pragma unroll
            for (int j = 0; j < 8; j++) fb[ns][j] = *(const bf16x8*)(pb[j] + ko);
#pragma unroll
            for (int i = 0; i < 4; i++)
#pragma unroll
                for (int j = 0; j < 8; j++)
                    acc[i][j] = MFMA16(fa[cs][i], fb[cs][j], acc[i][j]);
        }
#pragma unroll
        for (int i = 0; i < 4; i++) pa[i] += 128;
#pragma unroll
        for (int j = 0; j < 8; j++) pb[j] += 128;
    }
    // tail: 4 steps, prefetch only for u<3
#pragma unroll
    for (int u = 0; u < 4; u++) {
        const int cs = u & 1, ns = cs ^ 1;
        if (u < 3) {
            const int ko = (u + 1) * 32;
#pragma unroll
            for (int i = 0; i < 4; i++) fa[ns][i] = *(const bf16x8*)(pa[i] + ko);
#pragma unroll
            for (int j = 0; j < 8; j++) fb[ns][j] = *(const bf16x8*)(pb[j] + ko);
        }
#pragma unroll
        for (int i = 0; i < 4; i++)
#pragma unroll
            for (int j = 0; j < 8; j++)
                acc[i][j] = MFMA16(fa[cs][i], fb[cs][j], acc[i][j]);
    }

#pragma unroll
    for (int i = 0; i < 4; i++) {
#pragma unroll
        for (int r = 0; r < 4; r++) {
            int row = m0 + wm * 64 + i * 16 + hi * 4 + r;
#pragma unroll
            for (int j = 0; j < 8; j++) {
                int col = n0 + wn * 128 + j * 16 + fr;
                float v = acc[i][j][r];
                if (EPI == 2) ytmp[(size_t)row * DDIM + col] = f2bf(v);
                else          out[(size_t)row * DDIM + col] = v + bias2[col];
            }
        }
    }
}

// out[t] += wts[2t]*ytmp[inv[2t]] + wts[2t+1]*ytmp[inv[2t+1]]
__global__ __launch_bounds__(256) void k_combine(
    const u16* __restrict__ ytmp, const int* __restrict__ inv,
    const float* __restrict__ wts, float* __restrict__ out)
{
    int idx = blockIdx.x * 256 + threadIdx.x;
    int t = idx >> 7;
    int c = (idx & 127) * 4;
    int s0 = inv[2 * t], s1 = inv[2 * t + 1];
    float w0 = wts[2 * t], w1 = wts[2 * t + 1];
    ushort4 a = *(const ushort4*)&ytmp[(size_t)s0 * DDIM + c];
    ushort4 b = *(const ushort4*)&ytmp[(size_t)s1 * DDIM + c];
    float4 o = *(float4*)&out[(size_t)t * DDIM + c];
    o.x += w0 * bf2f(a.x) + w1 * bf2f(b.x);
    o.y += w0 * bf2f(a.y) + w1 * bf2f(b.y);
    o.z += w0 * bf2f(a.z) + w1 * bf2f(b.z);
    o.w += w0 * bf2f(a.w) + w1 * bf2f(b.w);
    *(float4*)&out[(size_t)t * DDIM + c] = o;
}

// ---------------- launch ----------------
extern "C" void kernel_launch(void* const* d_in, const int* in_sizes, int n_in,
                              void* d_out, int out_size, void* d_ws, size_t ws_size,
                              hipStream_t stream)
{
    const float* x   = (const float*)d_in[0];
    const float* gw  = (const float*)d_in[1];
    const float* w1  = (const float*)d_in[2];
    const float* w2  = (const float*)d_in[3];
    const float* w3  = (const float*)d_in[4];
    const float* sw1 = (const float*)d_in[5];
    const float* sb1 = (const float*)d_in[6];
    const float* sw2 = (const float*)d_in[7];
    const float* sb2 = (const float*)d_in[8];
    const float* sw3 = (const float*)d_in[9];
    const float* sb3 = (const float*)d_in[10];
    float* out = (float*)d_out;

    char* ws = (char*)d_ws;
    size_t off = 0;
    int*   topi    = (int*)(ws + off);   off += (size_t)2 * T_TOK * 4;
    float* wts     = (float*)(ws + off); off += (size_t)2 * T_TOK * 4;
    int*   perm    = (int*)(ws + off);   off += (size_t)MPAD * 4;
    float* pw      = (float*)(ws + off); off += (size_t)MPAD * 4;
    int*   cursors = (int*)(ws + off);   off += 256;
    int*   off_pad = (int*)(ws + off);   off += 256;
    int*   pcnt    = (int*)(ws + off);   off += (size_t)GBLK * NEXP * 4;
    float* pps     = (float*)(ws + off); off += (size_t)GBLK * NEXP * 4;
    int*   inv     = (int*)(ws + off);   off += (size_t)2 * T_TOK * 4;
    u16*   zpad    = (u16*)(ws + off);   off += 1024;
    u16*   xb      = (u16*)(ws + off);   off += (size_t)T_TOK * DDIM * 2;
    u16*   ytmp    = (u16*)(ws + off);   off += (size_t)MPAD * DDIM * 2;
    u16*   w1T     = (u16*)(ws + off);   off += (size_t)NEXP * IDIM * DDIM * 2;
    u16*   w3T     = (u16*)(ws + off);   off += (size_t)NEXP * IDIM * DDIM * 2;
    u16*   w2T     = (u16*)(ws + off);   off += (size_t)NEXP * DDIM * IDIM * 2;
    u16*   sw1T    = (u16*)(ws + off);   off += (size_t)SHDIM * DDIM * 2;
    u16*   sw3T    = (u16*)(ws + off);   off += (size_t)SHDIM * DDIM * 2;
    u16*   sw2T    = (u16*)(ws + off);   off += (size_t)DDIM * SHDIM * 2;
    u16*   hb      = (u16*)(ws + off);   off += (size_t)MPAD * IDIM * 2;   // shared h (16384x2048) fits too

    // routing
    k_gate<<<GBLK, 256, 0, stream>>>(x, gw, topi, wts, pcnt, pps, xb);
    k_scan<<<1, 64, 0, stream>>>(pcnt, pps, off_pad, out + (size_t)T_TOK * DDIM, cursors);
    k_fillperm<<<MPAD / 256, 256, 0, stream>>>(perm, zpad);
    k_scatter<<<T_TOK / 256, 256, 0, stream>>>(topi, wts, off_pad, cursors, perm, pw, inv);

    // weight transposes (fp32 -> bf16 [N][K])
    k_transpose<<<dim3(IDIM / 64, DDIM / 64, NEXP), 256, 0, stream>>>(w1, w1T, DDIM, IDIM);
    k_transpose<<<dim3(IDIM / 64, DDIM / 64, NEXP), 256, 0, stream>>>(w3, w3T, DDIM, IDIM);
    k_transpose<<<dim3(DDIM / 64, IDIM / 64, NEXP), 256, 0, stream>>>(w2, w2T, IDIM, DDIM);
    k_transpose<<<dim3(SHDIM / 64, DDIM / 64, 1), 256, 0, stream>>>(sw1, sw1T, DDIM, SHDIM);
    k_transpose<<<dim3(SHDIM / 64, DDIM / 64, 1), 256, 0, stream>>>(sw3, sw3T, DDIM, SHDIM);
    k_transpose<<<dim3(DDIM / 64, SHDIM / 64, 1), 256, 0, stream>>>(sw2, sw2T, SHDIM, DDIM);

    // shared expert (out = z)
    g_s1<false, true, SHDIM / 128><<<dim3(SHDIM / 128, T_TOK / 128), 256, 0, stream>>>(
        xb, sw1T, sw3T, sb1, sb3, hb, SHDIM, off_pad, nullptr, nullptr);
    g_s2<SHDIM, 1, DDIM / 256><<<dim3(DDIM / 256, T_TOK / 128), 256, 0, stream>>>(
        hb, sw2T, sb2, out, nullptr, off_pad);
    // routed experts (gather fused into fragment loads) -> ytmp, combine into out
    g_s1<true, false, IDIM / 128><<<dim3(IDIM / 128, MT_R), 256, 0, stream>>>(
        xb, w1T, w3T, nullptr, nullptr, hb, IDIM, off_pad, perm, zpad);
    g_s2<IDIM, 2, DDIM / 256><<<dim3(DDIM / 256, MT_R), 256, 0, stream>>>(
        hb, w2T, nullptr, nullptr, ytmp, off_pad);
    k_combine<<<(T_TOK * DDIM / 4) / 256, 256, 0, stream>>>(ytmp, inv, wts, out);
}

// Round 14
// 355.662 us; speedup vs baseline: 2.0527x; 2.0527x over previous
//
#include <hip/hip_runtime.h>
#include <math.h>
#include <stdint.h>

// B=8,S=2048,D=512,I=1024,E=8,K=2,SH=2048 ; T=16384 tokens
#define T_TOK 16384
#define DDIM  512
#define IDIM  1024
#define NEXP  8
#define SHDIM 2048
#define MT_R  264                  // routed M-tiles (2T + 8*127 padded to 128)
#define MPAD  (MT_R * 128)         // 33792 padded routed rows
#define GBLK  256                  // k_gate blocks (64 tokens each)

typedef unsigned short u16;
typedef short bf16x8 __attribute__((ext_vector_type(8)));
typedef float f32x4 __attribute__((ext_vector_type(4)));

__device__ __forceinline__ u16 f2bf(float f) {
    unsigned u = __float_as_uint(f);
    u += 0x7FFF + ((u >> 16) & 1);   // round-to-nearest-even
    return (u16)(u >> 16);
}
__device__ __forceinline__ float bf2f(u16 h) {
    return __uint_as_float((unsigned)h << 16);
}

__device__ __forceinline__ void gload_lds16(const void* g, void* l) {
    __builtin_amdgcn_global_load_lds(
        (const __attribute__((address_space(1))) void*)g,
        (__attribute__((address_space(3))) void*)l, 16, 0, 0);
}

// XCD-chunked bijective block swizzle (T1); nwg % 8 == 0 for all our grids.
__device__ __forceinline__ int xcd_swz(int id, int nwg) {
    return (id & 7) * (nwg >> 3) + (id >> 3);
}

// bank swizzle slot function (G4): rows r..r+15 cover each 16B slot exactly
// the structural minimum (verified R10: SQ_LDS_BANK_CONFLICT -> 0).
__device__ __forceinline__ int ksw(int r) { return (r >> 1) & 3; }

// ---------------- routing ----------------
__global__ void k_zero(int* cursors) {
    int i = threadIdx.x;
    if (i < NEXP) cursors[i] = 0;
}

// 64 tokens/block, 4 waves. No global atomics; fuses x->bf16 (writes xb).
__global__ __launch_bounds__(256) void k_gate(
    const float* __restrict__ x, const float* __restrict__ gw,
    int* __restrict__ topi, float* __restrict__ wts,
    int* __restrict__ pcnt, float* __restrict__ pps, u16* __restrict__ xb)
{
    __shared__ int   cnt[NEXP];
    __shared__ float ps[NEXP];
    const int tid = threadIdx.x;
    if (tid < NEXP) { cnt[tid] = 0; ps[tid] = 0.f; }
    __syncthreads();
    const int wid = tid >> 6, lane = tid & 63;

    const float4* gw4 = (const float4*)gw;
    float4 g0[NEXP], g1[NEXP];
#pragma unroll
    for (int e = 0; e < NEXP; e++) {
        g0[e] = gw4[e * 128 + lane];
        g1[e] = gw4[e * 128 + 64 + lane];
    }

    const int t0 = blockIdx.x * 64 + wid * 16;
    for (int u = 0; u < 16; u++) {
        int t = t0 + u;
        const float4* xr4 = (const float4*)(x + (size_t)t * DDIM);
        float4 v0 = xr4[lane];
        float4 v1 = xr4[64 + lane];
        ushort4 o0 = { f2bf(v0.x), f2bf(v0.y), f2bf(v0.z), f2bf(v0.w) };
        ushort4 o1 = { f2bf(v1.x), f2bf(v1.y), f2bf(v1.z), f2bf(v1.w) };
        ushort4* xbo = (ushort4*)(xb + (size_t)t * DDIM);
        xbo[lane] = o0;
        xbo[64 + lane] = o1;
        float acc[NEXP];
#pragma unroll
        for (int e = 0; e < NEXP; e++) {
            acc[e] = v0.x * g0[e].x + v0.y * g0[e].y + v0.z * g0[e].z + v0.w * g0[e].w
                   + v1.x * g1[e].x + v1.y * g1[e].y + v1.z * g1[e].z + v1.w * g1[e].w;
        }
#pragma unroll
        for (int e = 0; e < NEXP; e++) {
#pragma unroll
            for (int off = 32; off; off >>= 1) acc[e] += __shfl_xor(acc[e], off, 64);
        }
        if (lane == 0) {
            float s[NEXP];
#pragma unroll
            for (int e = 0; e < NEXP; e++) s[e] = 1.f / (1.f + expf(-acc[e]));
            int i1 = 0; float v1s = s[0];
#pragma unroll
            for (int e = 1; e < NEXP; e++) if (s[e] > v1s) { v1s = s[e]; i1 = e; }
            int i2 = -1; float v2s = -1.f;
#pragma unroll
            for (int e = 0; e < NEXP; e++) if (e != i1 && s[e] > v2s) { v2s = s[e]; i2 = e; }
            float inv = 1.f / (v1s + v2s);
            float wa = v1s * inv, wb = v2s * inv;  // ROUTE_SCALE = 1.0
            topi[2 * t] = i1; topi[2 * t + 1] = i2;
            wts[2 * t] = wa;  wts[2 * t + 1] = wb;
            atomicAdd(&cnt[i1], 1); atomicAdd(&cnt[i2], 1);   // LDS atomics
            atomicAdd(&ps[i1], wa); atomicAdd(&ps[i2], wb);
        }
    }
    __syncthreads();
    if (tid < NEXP) {
        pcnt[blockIdx.x * NEXP + tid] = cnt[tid];
        pps[blockIdx.x * NEXP + tid]  = ps[tid];
    }
}

// Reduce per-block partials; 128-padded exclusive prefix; aux loss.
__global__ void k_scan(const int* __restrict__ pcnt, const float* __restrict__ pps,
                       int* __restrict__ off_pad, float* __restrict__ out_loss)
{
    __shared__ int   scnt[8][NEXP];
    __shared__ float sps[8][NEXP];
    int tid = threadIdx.x;
    if (tid < 64) {
        int e = tid & 7, part = tid >> 3;
        int c = 0; float p = 0.f;
        for (int b = part * 32; b < part * 32 + 32; b++) {
            c += pcnt[b * NEXP + e];
            p += pps[b * NEXP + e];
        }
        scnt[part][e] = c; sps[part][e] = p;
    }
    __syncthreads();
    if (tid == 0) {
        int off = 0; float L = 0.f;
        for (int e = 0; e < NEXP; e++) {
            int c = 0; float p = 0.f;
            for (int q = 0; q < 8; q++) { c += scnt[q][e]; p += sps[q][e]; }
            off_pad[e] = off;
            off += (c + 127) & ~127;
            float f = (float)NEXP * (float)c / (float)(2 * T_TOK);
            L += f * (p / (float)T_TOK);
        }
        off_pad[NEXP] = off;
        out_loss[0] = L;
    }
}

// fills perm with -1; also zeroes the 512-elem bf16 zero-page
__global__ void k_fillperm(int* __restrict__ perm, u16* __restrict__ zpad) {
    int i = blockIdx.x * blockDim.x + threadIdx.x;
    if (i < MPAD) perm[i] = -1;
    if (blockIdx.x == 0 && threadIdx.x < 256) ((unsigned*)zpad)[threadIdx.x] = 0u;
}

// 256 tokens/block: LDS histogram -> one global atomicAdd per expert per block.
__global__ __launch_bounds__(256) void k_scatter(
    const int* __restrict__ topi, const float* __restrict__ wts,
    const int* __restrict__ off_pad, int* __restrict__ cursors,
    int* __restrict__ perm, float* __restrict__ pw, int* __restrict__ inv)
{
    __shared__ int lcnt[NEXP];
    __shared__ int lbase[NEXP];
    int tid = threadIdx.x;
    if (tid < NEXP) lcnt[tid] = 0;
    __syncthreads();
    int t = blockIdx.x * 256 + tid;
    int e0 = topi[2 * t], e1 = topi[2 * t + 1];
    int p0 = atomicAdd(&lcnt[e0], 1);
    int p1 = atomicAdd(&lcnt[e1], 1);
    __syncthreads();
    if (tid < NEXP) lbase[tid] = atomicAdd(&cursors[tid], lcnt[tid]);
    __syncthreads();
    int s0 = off_pad[e0] + lbase[e0] + p0;
    int s1 = off_pad[e1] + lbase[e1] + p1;
    perm[s0] = t; pw[s0] = wts[2 * t];
    perm[s1] = t; pw[s1] = wts[2 * t + 1];
    inv[2 * t] = s0; inv[2 * t + 1] = s1;
}

// dst[z][c][r] = bf16(src[z][r][c]) ; grid (C/64, R/64, nmat)
__global__ __launch_bounds__(256) void k_transpose(const float* __restrict__ src,
                                                   u16* __restrict__ dst, int R, int C)
{
    __shared__ u16 t[64][68];
    const float* s = src + (size_t)blockIdx.z * R * C;
    u16* d = dst + (size_t)blockIdx.z * R * C;
    int r0 = blockIdx.y * 64, c0 = blockIdx.x * 64;
    int tid = threadIdx.x;
    int lr = tid >> 4, lc = (tid & 15) * 4;
#pragma unroll
    for (int u = 0; u < 4; u++) {
        int r = lr + u * 16;
        float4 v = *(const float4*)&s[(size_t)(r0 + r) * C + c0 + lc];
        t[lc + 0][r] = f2bf(v.x);
        t[lc + 1][r] = f2bf(v.y);
        t[lc + 2][r] = f2bf(v.z);
        t[lc + 3][r] = f2bf(v.w);
    }
    __syncthreads();
    int wr = tid >> 4, wc = (tid & 15) * 4;
#pragma unroll
    for (int u = 0; u < 4; u++) {
        int c = wr + u * 16;
        ushort4 o = { t[c][wc], t[c][wc + 1], t[c][wc + 2], t[c][wc + 3] };
        *(ushort4*)&d[(size_t)(c0 + c) * R + r0 + wc] = o;
    }
}

// ---------------- s1: 128(M)x64(N) tile, BK=32, 3-buf, counted vmcnt, 3 blocks/CU ----------------
// Per buffer 16KB: A 8KB | B1 4KB | B3 4KB.
// Dual GEMM: H = bf16( silu(A@B1 [+b1]) * (A@B3 [+b3]) ).  A rows gathered via perm if ROUTED.
template<bool ROUTED, bool BIAS>
__global__ __launch_bounds__(256, 3) void k_s1(
    const u16* __restrict__ Axb, const u16* __restrict__ B1t, const u16* __restrict__ B3t,
    const float* __restrict__ bias1, const float* __restrict__ bias3,
    u16* __restrict__ H, int ldh, const int* __restrict__ off_pad,
    const int* __restrict__ perm, const u16* __restrict__ zpad)
{
    __shared__ __align__(16) unsigned char smem[3 * 16384];   // 48KB
    const int nwg = gridDim.x * gridDim.y;
    const int id  = xcd_swz(blockIdx.y * gridDim.x + blockIdx.x, nwg);
    const int m0 = (id / gridDim.x) * 128;
    const int n0 = (id % gridDim.x) * 64;
    if (ROUTED && m0 >= off_pad[NEXP]) return;
    const u16* b1 = B1t; const u16* b3 = B3t;
    if (ROUTED) {
        int e = 0;
        while (off_pad[e + 1] <= m0) e++;
        b1 += (size_t)e * IDIM * DDIM;
        b3 += (size_t)e * IDIM * DDIM;
    }
    const int tid = threadIdx.x;
    const int wid = tid >> 6, lane = tid & 63;
    const int fr = lane & 15, hi = lane >> 4;
    const int wrow = (wid >> 1) * 64, wcol = (wid & 1) * 32;

    // staging: A two sweeps (rows 0..127), B1/B3 one sweep (rows 0..63)
    const u16* ap[2]; const u16* b1p; const u16* b3p;
    int dstA[2];
#pragma unroll
    for (int s = 0; s < 2; s++) {
        int r = s * 64 + (tid >> 2);
        int goff = ((tid & 3) ^ ksw(r)) * 8;
        dstA[s] = s * 4096 + tid * 16;
        if (ROUTED) {
            int tok = perm[m0 + r];
            ap[s] = (tok >= 0 ? Axb + (size_t)tok * DDIM : zpad) + goff;
        } else {
            ap[s] = Axb + (size_t)(m0 + r) * DDIM + goff;
        }
    }
    {
        int rb = tid >> 2;
        int goffb = ((tid & 3) ^ ksw(rb)) * 8;
        b1p = b1 + (size_t)(n0 + rb) * DDIM + goffb;
        b3p = b3 + (size_t)(n0 + rb) * DDIM + goffb;
    }
    const int dstB = tid * 16;   // within 4KB region

    // fragment LDS byte offsets (swizzled read side)
    int aoff[4], boff[2];
#pragma unroll
    for (int i = 0; i < 4; i++) {
        int ar = wrow + i * 16 + fr;
        aoff[i] = ar * 64 + ((hi ^ ksw(ar)) << 4);
    }
#pragma unroll
    for (int j = 0; j < 2; j++) {
        int br = wcol + j * 16 + fr;
        boff[j] = br * 64 + ((hi ^ ksw(br)) << 4);
    }

    f32x4 acc1[4][2], acc3[4][2];
#pragma unroll
    for (int i = 0; i < 4; i++)
#pragma unroll
        for (int j = 0; j < 2; j++) { acc1[i][j] = {0.f, 0.f, 0.f, 0.f}; acc3[i][j] = {0.f, 0.f, 0.f, 0.f}; }

    const int NT = DDIM / 32;   // 16
    // prologue: stage tiles 0,1 (4 gloads each)
#pragma unroll
    for (int t = 0; t < 2; t++) {
        unsigned char* bb = smem + t * 16384;
        gload_lds16(ap[0] + t * 32, bb + dstA[0]);
        gload_lds16(ap[1] + t * 32, bb + dstA[1]);
        gload_lds16(b1p   + t * 32, bb + 8192  + dstB);
        gload_lds16(b3p   + t * 32, bb + 12288 + dstB);
    }

    int bufc = 0;
    for (int t = 0; t < NT; t++) {
        int bufn = bufc + 2; if (bufn >= 3) bufn -= 3;
        if (t + 2 < NT) {                     // stage tile t+2; 8 loads stay in flight
            unsigned char* bb = smem + bufn * 16384;
            int k2 = (t + 2) * 32;
            gload_lds16(ap[0] + k2, bb + dstA[0]);
            gload_lds16(ap[1] + k2, bb + dstA[1]);
            gload_lds16(b1p   + k2, bb + 8192  + dstB);
            gload_lds16(b3p   + k2, bb + 12288 + dstB);
            asm volatile("s_waitcnt vmcnt(8)" ::: "memory");   // tile t landed
        } else if (t + 2 == NT) {
            asm volatile("s_waitcnt vmcnt(4)" ::: "memory");
        } else {
            asm volatile("s_waitcnt vmcnt(0)" ::: "memory");
        }
        __builtin_amdgcn_s_barrier();
        __builtin_amdgcn_sched_barrier(0);
        const unsigned char* cb = smem + bufc * 16384;
        bf16x8 av[4], b1v[2], b3v[2];
#pragma unroll
        for (int i = 0; i < 4; i++) av[i] = *(const bf16x8*)(cb + aoff[i]);
#pragma unroll
        for (int j = 0; j < 2; j++) {
            b1v[j] = *(const bf16x8*)(cb + 8192  + boff[j]);
            b3v[j] = *(const bf16x8*)(cb + 12288 + boff[j]);
        }
        __builtin_amdgcn_s_setprio(1);
#pragma unroll
        for (int i = 0; i < 4; i++)
#pragma unroll
            for (int j = 0; j < 2; j++) {
                acc1[i][j] = __builtin_amdgcn_mfma_f32_16x16x32_bf16(av[i], b1v[j], acc1[i][j], 0, 0, 0);
                acc3[i][j] = __builtin_amdgcn_mfma_f32_16x16x32_bf16(av[i], b3v[j], acc3[i][j], 0, 0, 0);
            }
        __builtin_amdgcn_s_setprio(0);
        __builtin_amdgcn_sched_barrier(0);
        __builtin_amdgcn_s_barrier();        // reads of bufc retired before overwrite
        bufc++; if (bufc >= 3) bufc -= 3;
    }

    // wave-local SwiGLU epilogue
    const int rr = hi * 4;
#pragma unroll
    for (int i = 0; i < 4; i++) {
#pragma unroll
        for (int j = 0; j < 2; j++) {
            int col = n0 + wcol + j * 16 + fr;
            float bb1 = BIAS ? bias1[col] : 0.f;
            float bb3 = BIAS ? bias3[col] : 0.f;
#pragma unroll
            for (int r = 0; r < 4; r++) {
                int row = m0 + wrow + i * 16 + rr + r;
                float v1 = acc1[i][j][r] + bb1;
                float v3 = acc3[i][j][r] + bb3;
                float hv = (v1 / (1.f + __expf(-v1))) * v3;
                H[(size_t)row * ldh + col] = f2bf(hv);
            }
        }
    }
}

// ---------------- s2: 128x128 tile, BK=32, TRIPLE-buffered, counted vmcnt ----------------
template<int K, bool ROUTED>
__global__ __launch_bounds__(256, 3) void k_s2(
    const u16* __restrict__ A, const u16* __restrict__ Bt,
    const float* __restrict__ bias2, float* __restrict__ out,
    u16* __restrict__ ytmp, const int* __restrict__ off_pad)
{
    __shared__ __align__(16) unsigned char smem[3 * 16384];
    const int nwg = gridDim.x * gridDim.y;
    const int id  = xcd_swz(blockIdx.y * gridDim.x + blockIdx.x, nwg);
    const int m0 = (id / gridDim.x) * 128;
    const int n0 = (id % gridDim.x) * 128;
    if (ROUTED && m0 >= off_pad[NEXP]) return;
    const u16* bt = Bt;
    if (ROUTED) {
        int e = 0;
        while (off_pad[e + 1] <= m0) e++;
        bt += (size_t)e * DDIM * IDIM;
    }
    const int tid = threadIdx.x;
    const int wid = tid >> 6, lane = tid & 63;
    const int fr = lane & 15, hi = lane >> 4;
    const int wrow = (wid >> 1) * 64, wcol = (wid & 1) * 64;

    const u16* ap[2]; const u16* bp[2];
    int dst_[2];
#pragma unroll
    for (int s = 0; s < 2; s++) {
        int r = s * 64 + (tid >> 2);
        int goff = ((tid & 3) ^ ksw(r)) * 8;
        dst_[s] = s * 4096 + tid * 16;
        ap[s] = A  + (size_t)(m0 + r) * K + goff;
        bp[s] = bt + (size_t)(n0 + r) * K + goff;
    }
    int aoff[4], boff[4];
#pragma unroll
    for (int i = 0; i < 4; i++) {
        int ar = wrow + i * 16 + fr;
        aoff[i] = ar * 64 + ((hi ^ ksw(ar)) << 4);
        int br = wcol + i * 16 + fr;
        boff[i] = br * 64 + ((hi ^ ksw(br)) << 4);
    }

    f32x4 acc[4][4];
#pragma unroll
    for (int i = 0; i < 4; i++)
#pragma unroll
        for (int j = 0; j < 4; j++) acc[i][j] = {0.f, 0.f, 0.f, 0.f};

    const int NT = K / 32;
#pragma unroll
    for (int t = 0; t < 2; t++) {
        unsigned char* bb = smem + t * 16384;
#pragma unroll
        for (int s = 0; s < 2; s++) {
            gload_lds16(ap[s] + t * 32, bb + dst_[s]);
            gload_lds16(bp[s] + t * 32, bb + 8192 + dst_[s]);
        }
    }

    int bufc = 0;
    for (int t = 0; t < NT; t++) {
        int bufn = bufc + 2; if (bufn >= 3) bufn -= 3;
        if (t + 2 < NT) {
            unsigned char* bb = smem + bufn * 16384;
            int k2 = (t + 2) * 32;
#pragma unroll
            for (int s = 0; s < 2; s++) {
                gload_lds16(ap[s] + k2, bb + dst_[s]);
                gload_lds16(bp[s] + k2, bb + 8192 + dst_[s]);
            }
            asm volatile("s_waitcnt vmcnt(8)" ::: "memory");
        } else if (t + 2 == NT) {
            asm volatile("s_waitcnt vmcnt(4)" ::: "memory");
        } else {
            asm volatile("s_waitcnt vmcnt(0)" ::: "memory");
        }
        __builtin_amdgcn_s_barrier();
        __builtin_amdgcn_sched_barrier(0);
        const unsigned char* cb = smem + bufc * 16384;
        bf16x8 av[4], bv[4];
#pragma unroll
        for (int i = 0; i < 4; i++) {
            av[i] = *(const bf16x8*)(cb + aoff[i]);
            bv[i] = *(const bf16x8*)(cb + 8192 + boff[i]);
        }
        __builtin_amdgcn_s_setprio(1);
#pragma unroll
        for (int i = 0; i < 4; i++)
#pragma unroll
            for (int j = 0; j < 4; j++)
                acc[i][j] = __builtin_amdgcn_mfma_f32_16x16x32_bf16(av[i], bv[j], acc[i][j], 0, 0, 0);
        __builtin_amdgcn_s_setprio(0);
        __builtin_amdgcn_sched_barrier(0);
        __builtin_amdgcn_s_barrier();
        bufc++; if (bufc >= 3) bufc -= 3;
    }

    const int rr = hi * 4;
#pragma unroll
    for (int i = 0; i < 4; i++) {
#pragma unroll
        for (int r = 0; r < 4; r++) {
            int row = m0 + wrow + i * 16 + rr + r;
#pragma unroll
            for (int j = 0; j < 4; j++) {
                int col = n0 + wcol + j * 16 + fr;
                float v = acc[i][j][r];
                if (ROUTED) {
                    ytmp[(size_t)row * DDIM + col] = f2bf(v);
                } else {
                    out[(size_t)row * DDIM + col] = v + bias2[col];
                }
            }
        }
    }
}

// out[t] += wts[2t]*ytmp[inv[2t]] + wts[2t+1]*ytmp[inv[2t+1]]
__global__ __launch_bounds__(256) void k_combine(
    const u16* __restrict__ ytmp, const int* __restrict__ inv,
    const float* __restrict__ wts, float* __restrict__ out)
{
    int idx = blockIdx.x * 256 + threadIdx.x;
    int t = idx >> 7;
    int c = (idx & 127) * 4;
    int s0 = inv[2 * t], s1 = inv[2 * t + 1];
    float w0 = wts[2 * t], w1 = wts[2 * t + 1];
    ushort4 a = *(const ushort4*)&ytmp[(size_t)s0 * DDIM + c];
    ushort4 b = *(const ushort4*)&ytmp[(size_t)s1 * DDIM + c];
    float4 o = *(float4*)&out[(size_t)t * DDIM + c];
    o.x += w0 * bf2f(a.x) + w1 * bf2f(b.x);
    o.y += w0 * bf2f(a.y) + w1 * bf2f(b.y);
    o.z += w0 * bf2f(a.z) + w1 * bf2f(b.z);
    o.w += w0 * bf2f(a.w) + w1 * bf2f(b.w);
    *(float4*)&out[(size_t)t * DDIM + c] = o;
}

// ---------------- launch ----------------
extern "C" void kernel_launch(void* const* d_in, const int* in_sizes, int n_in,
                              void* d_out, int out_size, void* d_ws, size_t ws_size,
                              hipStream_t stream)
{
    const float* x   = (const float*)d_in[0];
    const float* gw  = (const float*)d_in[1];
    const float* w1  = (const float*)d_in[2];
    const float* w2  = (const float*)d_in[3];
    const float* w3  = (const float*)d_in[4];
    const float* sw1 = (const float*)d_in[5];
    const float* sb1 = (const float*)d_in[6];
    const float* sw2 = (const float*)d_in[7];
    const float* sb2 = (const float*)d_in[8];
    const float* sw3 = (const float*)d_in[9];
    const float* sb3 = (const float*)d_in[10];
    float* out = (float*)d_out;

    char* ws = (char*)d_ws;
    size_t off = 0;
    int*   topi    = (int*)(ws + off);   off += (size_t)2 * T_TOK * 4;
    float* wts     = (float*)(ws + off); off += (size_t)2 * T_TOK * 4;
    int*   perm    = (int*)(ws + off);   off += (size_t)MPAD * 4;
    float* pw      = (float*)(ws + off); off += (size_t)MPAD * 4;
    int*   cursors = (int*)(ws + off);   off += 256;
    int*   off_pad = (int*)(ws + off);   off += 256;
    int*   pcnt    = (int*)(ws + off);   off += (size_t)GBLK * NEXP * 4;
    float* pps     = (float*)(ws + off); off += (size_t)GBLK * NEXP * 4;
    int*   inv     = (int*)(ws + off);   off += (size_t)2 * T_TOK * 4;
    u16*   zpad    = (u16*)(ws + off);   off += 1024;
    u16*   xb      = (u16*)(ws + off);   off += (size_t)T_TOK * DDIM * 2;
    u16*   ytmp    = (u16*)(ws + off);   off += (size_t)MPAD * DDIM * 2;
    u16*   w1T     = (u16*)(ws + off);   off += (size_t)NEXP * IDIM * DDIM * 2;
    u16*   w3T     = (u16*)(ws + off);   off += (size_t)NEXP * IDIM * DDIM * 2;
    u16*   w2T     = (u16*)(ws + off);   off += (size_t)NEXP * DDIM * IDIM * 2;
    u16*   sw1T    = (u16*)(ws + off);   off += (size_t)SHDIM * DDIM * 2;
    u16*   sw3T    = (u16*)(ws + off);   off += (size_t)SHDIM * DDIM * 2;
    u16*   sw2T    = (u16*)(ws + off);   off += (size_t)DDIM * SHDIM * 2;
    u16*   hb      = (u16*)(ws + off);   off += (size_t)MPAD * IDIM * 2;   // shared h (16384x2048) fits too

    // routing
    k_zero<<<1, 64, 0, stream>>>(cursors);
    k_gate<<<GBLK, 256, 0, stream>>>(x, gw, topi, wts, pcnt, pps, xb);
    k_scan<<<1, 64, 0, stream>>>(pcnt, pps, off_pad, out + (size_t)T_TOK * DDIM);
    k_fillperm<<<MPAD / 256, 256, 0, stream>>>(perm, zpad);
    k_scatter<<<T_TOK / 256, 256, 0, stream>>>(topi, wts, off_pad, cursors, perm, pw, inv);

    // weight transposes (fp32 -> bf16 [N][K])
    k_transpose<<<dim3(IDIM / 64, DDIM / 64, NEXP), 256, 0, stream>>>(w1, w1T, DDIM, IDIM);
    k_transpose<<<dim3(IDIM / 64, DDIM / 64, NEXP), 256, 0, stream>>>(w3, w3T, DDIM, IDIM);
    k_transpose<<<dim3(DDIM / 64, IDIM / 64, NEXP), 256, 0, stream>>>(w2, w2T, IDIM, DDIM);
    k_transpose<<<dim3(SHDIM / 64, DDIM / 64, 1), 256, 0, stream>>>(sw1, sw1T, DDIM, SHDIM);
    k_transpose<<<dim3(SHDIM / 64, DDIM / 64, 1), 256, 0, stream>>>(sw3, sw3T, DDIM, SHDIM);
    k_transpose<<<dim3(DDIM / 64, SHDIM / 64, 1), 256, 0, stream>>>(sw2, sw2T, SHDIM, DDIM);

    // shared expert (out = z)
    k_s1<false, true><<<dim3(SHDIM / 64, T_TOK / 128), 256, 0, stream>>>(
        xb, sw1T, sw3T, sb1, sb3, hb, SHDIM, nullptr, nullptr, nullptr);
    k_s2<SHDIM, false><<<dim3(DDIM / 128, T_TOK / 128), 256, 0, stream>>>(
        hb, sw2T, sb2, out, nullptr, nullptr);
    // routed experts (gather fused into s1 staging) -> ytmp, combine into out
    k_s1<true, false><<<dim3(IDIM / 64, MT_R), 256, 0, stream>>>(
        xb, w1T, w3T, nullptr, nullptr, hb, IDIM, off_pad, perm, zpad);
    k_s2<IDIM, true><<<dim3(DDIM / 128, MT_R), 256, 0, stream>>>(
        hb, w2T, nullptr, nullptr, ytmp, off_pad);
    k_combine<<<(T_TOK * DDIM / 4) / 256, 256, 0, stream>>>(ytmp, inv, wts, out);
}